// Round 1
// 286.946 us; speedup vs baseline: 2.0689x; 2.0689x over previous
//
#include <hip/hip_runtime.h>
#include <stdint.h>

typedef unsigned short u16;
typedef __bf16 bf16x8 __attribute__((ext_vector_type(8)));
typedef float f32x4 __attribute__((ext_vector_type(4)));

#define T_SEQ 2048
#define KVH 4

__device__ __forceinline__ u16 f2b(float f) {
  uint32_t u = __builtin_bit_cast(uint32_t, f);
  u += 0x7FFFu + ((u >> 16) & 1u);
  return (u16)(u >> 16);
}
__device__ __forceinline__ float b2f(u16 h) {
  uint32_t u = ((uint32_t)h) << 16;
  return __builtin_bit_cast(float, u);
}

__device__ __forceinline__ void gload16(const void* g, void* l) {
  __builtin_amdgcn_global_load_lds((const __attribute__((address_space(1))) void*)g,
                                   (__attribute__((address_space(3))) void*)l, 16, 0, 0);
}

// ---------------- fp32 -> bf16 convert (x) ----------------
__global__ void k_f32_to_bf16(const float* __restrict__ in, u16* __restrict__ out, int n4) {
  int i = blockIdx.x * blockDim.x + threadIdx.x;
  if (i >= n4) return;
  float4 v = reinterpret_cast<const float4*>(in)[i];
  ushort4 o;
  o.x = f2b(v.x); o.y = f2b(v.y); o.z = f2b(v.z); o.w = f2b(v.w);
  reinterpret_cast<ushort4*>(out)[i] = o;
}

// ---------------- tiled transpose fp32[R][C] -> bf16[C][R] ----------------
__global__ void k_transpose_f32_bf16(const float* __restrict__ in, u16* __restrict__ out,
                                     int R, int Cc) {
  __shared__ float tile[32][33];
  const int c0 = blockIdx.x * 32, r0 = blockIdx.y * 32;
  const int tx = threadIdx.x, ty = threadIdx.y;
  for (int i = ty; i < 32; i += 8) tile[i][tx] = in[(size_t)(r0 + i) * Cc + c0 + tx];
  __syncthreads();
  for (int i = ty; i < 32; i += 8) out[(size_t)(c0 + i) * R + r0 + tx] = f2b(tile[tx][i]);
}

// ---------------- bf16 GEMM: C[M][N] = A[M][K] * Bt[N][K]^T ----------------
// 128x128 tile, 4 waves (2x2), BK=32, 16x16x32 MFMA, global_load_lds staging.
template <int OUT_BF16>
__global__ __launch_bounds__(256, 2) void k_gemm(const u16* __restrict__ A,
                                                 const u16* __restrict__ Bt,
                                                 void* __restrict__ Cp,
                                                 int M, int N, int Kd,
                                                 int lda, int ldb, int ldc) {
  __align__(16) __shared__ u16 As[128 * 32];
  __align__(16) __shared__ u16 Bs[128 * 32];
  const int tid = threadIdx.x;
  const int wid = tid >> 6, lane = tid & 63;
  const int lg = lane >> 4, lm = lane & 15;
  const int bm = blockIdx.x, bn = blockIdx.y;
  const int wr = wid >> 1, wc = wid & 1;

  const int srow = wid * 32 + (lane >> 2);
  const int scol = (lane & 3) * 8;
  const u16* ap0 = A + (size_t)(bm * 128 + srow) * lda + scol;
  const u16* ap1 = ap0 + (size_t)16 * lda;
  const u16* bp0 = Bt + (size_t)(bn * 128 + srow) * ldb + scol;
  const u16* bp1 = bp0 + (size_t)16 * ldb;
  u16* asDst0 = As + wid * 1024;
  u16* asDst1 = As + wid * 1024 + 512;
  u16* bsDst0 = Bs + wid * 1024;
  u16* bsDst1 = Bs + wid * 1024 + 512;

  const f32x4 z4 = {0.f, 0.f, 0.f, 0.f};
  f32x4 acc[4][4];
#pragma unroll
  for (int i = 0; i < 4; ++i)
#pragma unroll
    for (int j = 0; j < 4; ++j) acc[i][j] = z4;

  const int nk = Kd >> 5;
  for (int kb = 0; kb < nk; ++kb) {
    gload16(ap0, asDst0);
    gload16(ap1, asDst1);
    gload16(bp0, bsDst0);
    gload16(bp1, bsDst1);
    ap0 += 32; ap1 += 32; bp0 += 32; bp1 += 32;
    __syncthreads();
    bf16x8 af[4], bfr[4];
#pragma unroll
    for (int i = 0; i < 4; ++i)
      af[i] = *(const bf16x8*)(As + (wr * 64 + i * 16 + lm) * 32 + lg * 8);
#pragma unroll
    for (int j = 0; j < 4; ++j)
      bfr[j] = *(const bf16x8*)(Bs + (wc * 64 + j * 16 + lm) * 32 + lg * 8);
#pragma unroll
    for (int i = 0; i < 4; ++i)
#pragma unroll
      for (int j = 0; j < 4; ++j)
        acc[i][j] = __builtin_amdgcn_mfma_f32_16x16x32_bf16(af[i], bfr[j], acc[i][j], 0, 0, 0);
    __syncthreads();
  }

#pragma unroll
  for (int i = 0; i < 4; ++i) {
    const int row = bm * 128 + wr * 64 + i * 16 + lg * 4;
#pragma unroll
    for (int j = 0; j < 4; ++j) {
      const int col = bn * 128 + wc * 64 + j * 16 + lm;
#pragma unroll
      for (int r = 0; r < 4; ++r) {
        const float v = acc[i][j][r];
        if (OUT_BF16)
          ((u16*)Cp)[(size_t)(row + r) * ldc + col] = f2b(v);
        else
          ((float*)Cp)[(size_t)(row + r) * ldc + col] = v;
      }
    }
  }
}

// ---------------- RoPE for Q (+ fold 1/sqrt(H) scale) ----------------
__global__ void k_rope_q(const u16* __restrict__ qkv, u16* __restrict__ qbf) {
  const int idx = blockIdx.x * 256 + threadIdx.x;  // B*T*N*64 threads
  const int j = idx & 63;
  const int n = (idx >> 6) & 15;
  const int m = idx >> 10;  // b*T + t
  const int t = m & (T_SEQ - 1);
  const float inv = __expf((float)j * -0.14391157f);  // 10000^(-j/64)
  const float ang = (float)t * inv;
  float s, c;
  __sincosf(ang, &s, &c);
  const u16* row = qkv + (size_t)m * 3072 + n * 128;
  const float x1 = b2f(row[j]), x2 = b2f(row[j + 64]);
  const float scale = 0.08838834764831845f;  // 1/sqrt(128)
  u16* orow = qbf + (size_t)m * 2048 + n * 128;
  orow[j] = f2b((x1 * c - x2 * s) * scale);
  orow[j + 64] = f2b((x2 * c + x1 * s) * scale);
}

// ---------------- RoPE for K, layout [b][kh][t][h] ----------------
__global__ void k_rope_k(const u16* __restrict__ qkv, u16* __restrict__ kbf) {
  const int idx = blockIdx.x * 256 + threadIdx.x;  // B*T*KVH*64 threads
  const int j = idx & 63;
  const int kh = (idx >> 6) & 3;
  const int m = idx >> 8;  // b*T + t
  const int t = m & (T_SEQ - 1);
  const int b = m >> 11;
  const float inv = __expf((float)j * -0.14391157f);
  const float ang = (float)t * inv;
  float s, c;
  __sincosf(ang, &s, &c);
  const u16* row = qkv + (size_t)m * 3072 + 2048 + kh * 128;
  const float x1 = b2f(row[j]), x2 = b2f(row[j + 64]);
  u16* orow = kbf + ((size_t)(b * KVH + kh) * T_SEQ + t) * 128;
  orow[j] = f2b(x1 * c - x2 * s);
  orow[j + 64] = f2b(x2 * c + x1 * s);
}

// ---------------- V transpose: qkv[.,2560+kh*128+h] -> vt[b][kh][h][t] ----------------
__global__ void k_v_transpose(const u16* __restrict__ qkv, u16* __restrict__ vt) {
  __shared__ u16 tile[32][33];
  const int t0 = blockIdx.x * 32, h0 = blockIdx.y * 32, bk = blockIdx.z;
  const int b = bk >> 2, kh = bk & 3;
  const int tx = threadIdx.x, ty = threadIdx.y;
  for (int i = ty; i < 32; i += 8)
    tile[i][tx] = qkv[(size_t)(b * T_SEQ + t0 + i) * 3072 + 2560 + kh * 128 + h0 + tx];
  __syncthreads();
  for (int i = ty; i < 32; i += 8)
    vt[(size_t)bk * (128 * T_SEQ) + (size_t)(h0 + i) * T_SEQ + t0 + tx] = tile[tx][i];
}

// ---------------- Flash attention with tanh softcap + causal ----------------
// grid (T/64, N=16, B=2), 4 waves; each wave = one 16-row Q tile, KVBLK=64.
// K[64][128] and V[128][64] tiles staged in double-buffered, XOR-swizzled LDS
// via global_load_lds (pre-swizzled global source, linear LDS dest), shared by
// all 4 waves. 2-phase pipeline: issue next-tile stage, compute current, drain.
// Swapped QK^T: lane (lm,lg) holds S[t=q0+lm][s=kv+st*16+lg*4+r].
__global__ __launch_bounds__(256, 2) void k_attn(const u16* __restrict__ qbf,
                                                 const u16* __restrict__ kbf,
                                                 const u16* __restrict__ vt,
                                                 u16* __restrict__ enc) {
  // LDS: Ks dbuf 2*16KB | Vs dbuf 2*16KB | Pl 4 waves * 2KB  = 73728 B
  __shared__ __align__(16) u16 smem[36864];
  u16* const Ks0 = smem;            // + buf*8192
  u16* const Vs0 = smem + 16384;    // + buf*8192

  const int qt = blockIdx.x, n = blockIdx.y, b = blockIdx.z;
  const int kh = n >> 2;
  const int tid = threadIdx.x;
  const int wid = tid >> 6;
  const int lane = tid & 63;
  const int lg = lane >> 4;
  const int lm = lane & 15;
  const int q0 = qt * 64 + wid * 16;
  u16* const Pl = smem + 32768 + wid * 1024;  // [16][64] bf16, swizzled

  // Q fragments (scale already folded in by k_rope_q)
  bf16x8 qf[4];
  {
    const u16* qrow = qbf + (size_t)(b * T_SEQ + q0 + lm) * 2048 + n * 128 + lg * 8;
#pragma unroll
    for (int c = 0; c < 4; ++c) qf[c] = *(const bf16x8*)(qrow + c * 32);
  }
  const u16* const kg = kbf + (size_t)(b * KVH + kh) * T_SEQ * 128;
  const u16* const vg = vt + (size_t)(b * KVH + kh) * 128 * T_SEQ;

  // precomputed swizzled LDS read offsets (elements); swizzle: 16B-unit ^= (row&7)
  const int swz = lm & 7;
  int koff[4], voff[2], poff[4];
#pragma unroll
  for (int c = 0; c < 4; ++c) koff[c] = lm * 128 + (((c * 4 + lg) ^ swz) * 8);
#pragma unroll
  for (int ks = 0; ks < 2; ++ks) voff[ks] = lm * 64 + (((ks * 4 + lg) ^ swz) * 8);
#pragma unroll
  for (int st = 0; st < 4; ++st)
    poff[st] = lm * 64 + (((st * 2 + (lg >> 1)) ^ swz) * 8) + (lg & 1) * 4;

  const f32x4 z4 = {0.f, 0.f, 0.f, 0.f};
  f32x4 acc_o[8];
#pragma unroll
  for (int h = 0; h < 8; ++h) acc_o[h] = z4;
  float m_run = -3.0e38f, l_run = 0.f;

  const int ntiles = qt + 1;

  // stage tile kb2 into buffer buf: K rows 256B (16 units), V rows 128B (8 units);
  // linear LDS dest, inverse-swizzled global source (G21: both-sides-or-neither).
  auto STAGE = [&](int buf, int kb2) {
    const int kv2 = kb2 * 64;
    const u16* ksrc = kg + (size_t)kv2 * 128;
    u16* kdst = Ks0 + buf * 8192;
    u16* vdst = Vs0 + buf * 8192;
#pragma unroll
    for (int i = 0; i < 4; ++i) {
      const int g = tid + i * 256;
      const int row = g >> 4, u = g & 15;
      gload16(ksrc + row * 128 + ((u ^ (row & 7)) * 8), kdst + g * 8);
    }
#pragma unroll
    for (int i = 0; i < 4; ++i) {
      const int g = tid + i * 256;
      const int row = g >> 3, u = g & 7;
      gload16(vg + (size_t)row * T_SEQ + kv2 + ((u ^ (row & 7)) * 8), vdst + g * 8);
    }
  };

  STAGE(0, 0);
  asm volatile("s_waitcnt vmcnt(0)" ::: "memory");
  __syncthreads();

  for (int kb = 0; kb < ntiles; ++kb) {
    const int cur = kb & 1;
    if (kb + 1 < ntiles) STAGE(cur ^ 1, kb + 1);
    const u16* KsC = Ks0 + cur * 8192;
    const u16* VsC = Vs0 + cur * 8192;

    // QK^T: sa[st][r] = S[t=q0+lm][s=kv+st*16+lg*4+r]
    f32x4 sa[4] = {z4, z4, z4, z4};
    __builtin_amdgcn_s_setprio(1);
#pragma unroll
    for (int st = 0; st < 4; ++st) {
#pragma unroll
      for (int c = 0; c < 4; ++c) {
        const bf16x8 kf = *(const bf16x8*)(KsC + st * 2048 + koff[c]);
        sa[st] = __builtin_amdgcn_mfma_f32_16x16x32_bf16(kf, qf[c], sa[st], 0, 0, 0);
      }
    }
    __builtin_amdgcn_s_setprio(0);

    float p[16];
#pragma unroll
    for (int st = 0; st < 4; ++st)
#pragma unroll
      for (int r = 0; r < 4; ++r) p[st * 4 + r] = sa[st][r];
    // softcap: 50*tanh(x/50) = 50 - 100/(exp(x/25)+1)
#pragma unroll
    for (int i = 0; i < 16; ++i) {
      const float e = __expf(p[i] * 0.04f);
      p[i] = 50.f - 100.f * __builtin_amdgcn_rcpf(e + 1.f);
    }
    if (kb == ntiles - 1) {  // diagonal tile: causal mask
      const int tg = q0 + lm;
      const int kv = kb * 64;
#pragma unroll
      for (int i = 0; i < 16; ++i) {
        const int sg = kv + (i >> 2) * 16 + lg * 4 + (i & 3);
        if (sg > tg) p[i] = -3.0e38f;
      }
    }
    float mt = p[0];
#pragma unroll
    for (int i = 1; i < 16; ++i) mt = fmaxf(mt, p[i]);
    mt = fmaxf(mt, __shfl_xor(mt, 16));
    mt = fmaxf(mt, __shfl_xor(mt, 32));
    const float m_new = fmaxf(m_run, mt);
    const float alpha = __expf(m_run - m_new);
    float rs = 0.f;
#pragma unroll
    for (int i = 0; i < 16; ++i) {
      p[i] = __expf(p[i] - m_new);
      rs += p[i];
    }
    rs += __shfl_xor(rs, 16);
    rs += __shfl_xor(rs, 32);
    l_run = l_run * alpha + rs;
    m_run = m_new;

    // P -> LDS (bf16, swizzled), lane-exchange to A-fragment layout
#pragma unroll
    for (int st = 0; st < 4; ++st) {
      ushort4 w4;
      w4.x = f2b(p[st * 4 + 0]);
      w4.y = f2b(p[st * 4 + 1]);
      w4.z = f2b(p[st * 4 + 2]);
      w4.w = f2b(p[st * 4 + 3]);
      *(ushort4*)(Pl + poff[st]) = w4;
    }
    asm volatile("s_waitcnt lgkmcnt(0)" ::: "memory");
    bf16x8 pf[2];
#pragma unroll
    for (int ks = 0; ks < 2; ++ks) pf[ks] = *(const bf16x8*)(Pl + voff[ks]);

    // rescale accumulator (alpha is per-row t=lm; output rows are lg*4+r)
    float af[4];
#pragma unroll
    for (int r = 0; r < 4; ++r) af[r] = __shfl(alpha, lg * 4 + r);
#pragma unroll
    for (int h = 0; h < 8; ++h) {
      acc_o[h][0] *= af[0];
      acc_o[h][1] *= af[1];
      acc_o[h][2] *= af[2];
      acc_o[h][3] *= af[3];
    }
    // PV from swizzled LDS V tile
    __builtin_amdgcn_s_setprio(1);
#pragma unroll
    for (int h = 0; h < 8; ++h) {
#pragma unroll
      for (int ks = 0; ks < 2; ++ks) {
        const bf16x8 vf = *(const bf16x8*)(VsC + h * 1024 + voff[ks]);
        acc_o[h] = __builtin_amdgcn_mfma_f32_16x16x32_bf16(pf[ks], vf, acc_o[h], 0, 0, 0);
      }
    }
    __builtin_amdgcn_s_setprio(0);

    asm volatile("s_waitcnt vmcnt(0)" ::: "memory");  // next-tile staging landed
    __syncthreads();
  }

  float li[4];
#pragma unroll
  for (int r = 0; r < 4; ++r) li[r] = 1.f / __shfl(l_run, lg * 4 + r);
#pragma unroll
  for (int h = 0; h < 8; ++h) {
#pragma unroll
    for (int r = 0; r < 4; ++r) {
      enc[(size_t)(b * T_SEQ + q0 + lg * 4 + r) * 2048 + n * 128 + h * 16 + lm] =
          f2b(acc_o[h][r] * li[r]);
    }
  }
}

extern "C" void kernel_launch(void* const* d_in, const int* in_sizes, int n_in,
                              void* d_out, int out_size, void* d_ws, size_t ws_size,
                              hipStream_t stream) {
  const float* x  = (const float*)d_in[0];
  const float* wq = (const float*)d_in[1];
  const float* wk = (const float*)d_in[2];
  const float* wv = (const float*)d_in[3];
  const float* wo = (const float*)d_in[4];

  char* ws = (char*)d_ws;
  u16* x_bf  = (u16*)(ws);                    // 16,777,216 B
  u16* wqkvt = (u16*)(ws + 16777216);         // 12,582,912 B  [3072][2048]
  u16* wot   = (u16*)(ws + 29360128);         //  8,388,608 B  [2048][2048]
  u16* qkv   = (u16*)(ws + 37748736);         // 25,165,824 B  [4096][3072]
  u16* enc   = qkv;                           // aliases qkv (dead by then)
  u16* q_bf  = (u16*)(ws + 62914560);         // 16,777,216 B  [4096][2048]
  u16* k_bf  = (u16*)(ws + 79691776);         //  4,194,304 B  [b][kh][t][h]
  u16* vt    = (u16*)(ws + 83886080);         //  4,194,304 B  [b][kh][h][t]
  if (ws_size < 88080384) return;             // need 84 MiB scratch
  (void)in_sizes; (void)n_in; (void)out_size;

  // 1) x -> bf16
  k_f32_to_bf16<<<dim3(8192), dim3(256), 0, stream>>>(x, x_bf, 8388608 / 4);
  // 2) weight transposes (fp32 [K][N] -> bf16 [N][K])
  k_transpose_f32_bf16<<<dim3(64, 64), dim3(32, 8), 0, stream>>>(wq, wqkvt, 2048, 2048);
  k_transpose_f32_bf16<<<dim3(16, 64), dim3(32, 8), 0, stream>>>(wk, wqkvt + 2048 * 2048, 2048, 512);
  k_transpose_f32_bf16<<<dim3(16, 64), dim3(32, 8), 0, stream>>>(wv, wqkvt + 2560 * 2048, 2048, 512);
  k_transpose_f32_bf16<<<dim3(64, 64), dim3(32, 8), 0, stream>>>(wo, wot, 2048, 2048);
  // 3) fused QKV projection: [4096][3072]
  k_gemm<1><<<dim3(32, 24), dim3(256), 0, stream>>>(x_bf, wqkvt, qkv,
                                                    4096, 3072, 2048, 2048, 2048, 3072);
  // 4) RoPE + layout shuffles
  k_rope_q<<<dim3(16384), dim3(256), 0, stream>>>(qkv, q_bf);
  k_rope_k<<<dim3(4096), dim3(256), 0, stream>>>(qkv, k_bf);
  k_v_transpose<<<dim3(64, 4, 8), dim3(32, 8), 0, stream>>>(qkv, vt);
  // 5) flash attention -> enc [4096][2048] bf16
  k_attn<<<dim3(32, 16, 2), dim3(256), 0, stream>>>(q_bf, k_bf, vt, enc);
  // 6) output projection -> d_out fp32
  k_gemm<0><<<dim3(32, 16), dim3(256), 0, stream>>>(enc, wot, d_out,
                                                    4096, 2048, 2048, 2048, 2048, 2048);
}

// Round 2
// 266.727 us; speedup vs baseline: 2.2257x; 1.0758x over previous
//
#include <hip/hip_runtime.h>
#include <stdint.h>

typedef unsigned short u16;
typedef __bf16 bf16x8 __attribute__((ext_vector_type(8)));
typedef float f32x4 __attribute__((ext_vector_type(4)));

#define T_SEQ 2048
#define KVH 4

__device__ __forceinline__ u16 f2b(float f) {
  uint32_t u = __builtin_bit_cast(uint32_t, f);
  u += 0x7FFFu + ((u >> 16) & 1u);
  return (u16)(u >> 16);
}
__device__ __forceinline__ float b2f(u16 h) {
  uint32_t u = ((uint32_t)h) << 16;
  return __builtin_bit_cast(float, u);
}

__device__ __forceinline__ void gload16(const void* g, void* l) {
  __builtin_amdgcn_global_load_lds((const __attribute__((address_space(1))) void*)g,
                                   (__attribute__((address_space(3))) void*)l, 16, 0, 0);
}

// ---------------- fp32 -> bf16 convert (x) ----------------
__global__ void k_f32_to_bf16(const float* __restrict__ in, u16* __restrict__ out, int n4) {
  int i = blockIdx.x * blockDim.x + threadIdx.x;
  if (i >= n4) return;
  float4 v = reinterpret_cast<const float4*>(in)[i];
  ushort4 o;
  o.x = f2b(v.x); o.y = f2b(v.y); o.z = f2b(v.z); o.w = f2b(v.w);
  reinterpret_cast<ushort4*>(out)[i] = o;
}

// ---------------- tiled transpose fp32[R][C] -> bf16[C][R] ----------------
__global__ void k_transpose_f32_bf16(const float* __restrict__ in, u16* __restrict__ out,
                                     int R, int Cc) {
  __shared__ float tile[32][33];
  const int c0 = blockIdx.x * 32, r0 = blockIdx.y * 32;
  const int tx = threadIdx.x, ty = threadIdx.y;
  for (int i = ty; i < 32; i += 8) tile[i][tx] = in[(size_t)(r0 + i) * Cc + c0 + tx];
  __syncthreads();
  for (int i = ty; i < 32; i += 8) out[(size_t)(c0 + i) * R + r0 + tx] = f2b(tile[tx][i]);
}

// ---------------- bf16 GEMM: C[M][N] = A[M][K] * Bt[N][K]^T ----------------
// 128x128 tile, 4 waves (2x2), BK=32, 16x16x32 MFMA, global_load_lds staging.
template <int OUT_BF16>
__global__ __launch_bounds__(256, 2) void k_gemm(const u16* __restrict__ A,
                                                 const u16* __restrict__ Bt,
                                                 void* __restrict__ Cp,
                                                 int M, int N, int Kd,
                                                 int lda, int ldb, int ldc) {
  __align__(16) __shared__ u16 As[128 * 32];
  __align__(16) __shared__ u16 Bs[128 * 32];
  const int tid = threadIdx.x;
  const int wid = tid >> 6, lane = tid & 63;
  const int lg = lane >> 4, lm = lane & 15;
  const int bm = blockIdx.x, bn = blockIdx.y;
  const int wr = wid >> 1, wc = wid & 1;

  const int srow = wid * 32 + (lane >> 2);
  const int scol = (lane & 3) * 8;
  const u16* ap0 = A + (size_t)(bm * 128 + srow) * lda + scol;
  const u16* ap1 = ap0 + (size_t)16 * lda;
  const u16* bp0 = Bt + (size_t)(bn * 128 + srow) * ldb + scol;
  const u16* bp1 = bp0 + (size_t)16 * ldb;
  u16* asDst0 = As + wid * 1024;
  u16* asDst1 = As + wid * 1024 + 512;
  u16* bsDst0 = Bs + wid * 1024;
  u16* bsDst1 = Bs + wid * 1024 + 512;

  const f32x4 z4 = {0.f, 0.f, 0.f, 0.f};
  f32x4 acc[4][4];
#pragma unroll
  for (int i = 0; i < 4; ++i)
#pragma unroll
    for (int j = 0; j < 4; ++j) acc[i][j] = z4;

  const int nk = Kd >> 5;
  for (int kb = 0; kb < nk; ++kb) {
    gload16(ap0, asDst0);
    gload16(ap1, asDst1);
    gload16(bp0, bsDst0);
    gload16(bp1, bsDst1);
    ap0 += 32; ap1 += 32; bp0 += 32; bp1 += 32;
    __syncthreads();
    bf16x8 af[4], bfr[4];
#pragma unroll
    for (int i = 0; i < 4; ++i)
      af[i] = *(const bf16x8*)(As + (wr * 64 + i * 16 + lm) * 32 + lg * 8);
#pragma unroll
    for (int j = 0; j < 4; ++j)
      bfr[j] = *(const bf16x8*)(Bs + (wc * 64 + j * 16 + lm) * 32 + lg * 8);
#pragma unroll
    for (int i = 0; i < 4; ++i)
#pragma unroll
      for (int j = 0; j < 4; ++j)
        acc[i][j] = __builtin_amdgcn_mfma_f32_16x16x32_bf16(af[i], bfr[j], acc[i][j], 0, 0, 0);
    __syncthreads();
  }

#pragma unroll
  for (int i = 0; i < 4; ++i) {
    const int row = bm * 128 + wr * 64 + i * 16 + lg * 4;
#pragma unroll
    for (int j = 0; j < 4; ++j) {
      const int col = bn * 128 + wc * 64 + j * 16 + lm;
#pragma unroll
      for (int r = 0; r < 4; ++r) {
        const float v = acc[i][j][r];
        if (OUT_BF16)
          ((u16*)Cp)[(size_t)(row + r) * ldc + col] = f2b(v);
        else
          ((float*)Cp)[(size_t)(row + r) * ldc + col] = v;
      }
    }
  }
}

// ---------------- RoPE for Q (+ fold 1/sqrt(H) scale) ----------------
__global__ void k_rope_q(const u16* __restrict__ qkv, u16* __restrict__ qbf) {
  const int idx = blockIdx.x * 256 + threadIdx.x;  // B*T*N*64 threads
  const int j = idx & 63;
  const int n = (idx >> 6) & 15;
  const int m = idx >> 10;  // b*T + t
  const int t = m & (T_SEQ - 1);
  const float inv = __expf((float)j * -0.14391157f);  // 10000^(-j/64)
  const float ang = (float)t * inv;
  float s, c;
  __sincosf(ang, &s, &c);
  const u16* row = qkv + (size_t)m * 3072 + n * 128;
  const float x1 = b2f(row[j]), x2 = b2f(row[j + 64]);
  const float scale = 0.08838834764831845f;  // 1/sqrt(128)
  u16* orow = qbf + (size_t)m * 2048 + n * 128;
  orow[j] = f2b((x1 * c - x2 * s) * scale);
  orow[j + 64] = f2b((x2 * c + x1 * s) * scale);
}

// ---------------- RoPE for K, layout [b][kh][t][h] ----------------
__global__ void k_rope_k(const u16* __restrict__ qkv, u16* __restrict__ kbf) {
  const int idx = blockIdx.x * 256 + threadIdx.x;  // B*T*KVH*64 threads
  const int j = idx & 63;
  const int kh = (idx >> 6) & 3;
  const int m = idx >> 8;  // b*T + t
  const int t = m & (T_SEQ - 1);
  const int b = m >> 11;
  const float inv = __expf((float)j * -0.14391157f);
  const float ang = (float)t * inv;
  float s, c;
  __sincosf(ang, &s, &c);
  const u16* row = qkv + (size_t)m * 3072 + 2048 + kh * 128;
  const float x1 = b2f(row[j]), x2 = b2f(row[j + 64]);
  u16* orow = kbf + ((size_t)(b * KVH + kh) * T_SEQ + t) * 128;
  orow[j] = f2b(x1 * c - x2 * s);
  orow[j + 64] = f2b(x2 * c + x1 * s);
}

// ---------------- V transpose: qkv[.,2560+kh*128+h] -> vt[b][kh][h][t] ----------------
__global__ void k_v_transpose(const u16* __restrict__ qkv, u16* __restrict__ vt) {
  __shared__ u16 tile[32][33];
  const int t0 = blockIdx.x * 32, h0 = blockIdx.y * 32, bk = blockIdx.z;
  const int b = bk >> 2, kh = bk & 3;
  const int tx = threadIdx.x, ty = threadIdx.y;
  for (int i = ty; i < 32; i += 8)
    tile[i][tx] = qkv[(size_t)(b * T_SEQ + t0 + i) * 3072 + 2560 + kh * 128 + h0 + tx];
  __syncthreads();
  for (int i = ty; i < 32; i += 8)
    vt[(size_t)bk * (128 * T_SEQ) + (size_t)(h0 + i) * T_SEQ + t0 + tx] = tile[tx][i];
}

// ---------------- Flash attention with tanh softcap + causal ----------------
// grid (T/128, N=16, B=2), 4 waves x 32 Q rows (two 16-row sub-tiles A,B).
// K[64][128], V[128][64] staged dbuf+swizzled LDS (global_load_lds), shared by
// all 4 waves; each kf/vf LDS read feeds TWO MFMAs (register reuse across A,B).
// Longest-first block order (qt = 15 - bx). Swapped QK^T as before.
__global__ __launch_bounds__(256, 2) void k_attn(const u16* __restrict__ qbf,
                                                 const u16* __restrict__ kbf,
                                                 const u16* __restrict__ vt,
                                                 u16* __restrict__ enc) {
  // LDS: Ks dbuf 2*16KB | Vs dbuf 2*16KB | Pl 4 waves * 2KB  = 73728 B
  __shared__ __align__(16) u16 smem[36864];
  u16* const Ks0 = smem;            // + buf*8192
  u16* const Vs0 = smem + 16384;    // + buf*8192

  const int qt = 15 - blockIdx.x;   // longest-work blocks dispatch first (LPT)
  const int n = blockIdx.y, b = blockIdx.z;
  const int kh = n >> 2;
  const int tid = threadIdx.x;
  const int wid = tid >> 6;
  const int lane = tid & 63;
  const int lg = lane >> 4;
  const int lm = lane & 15;
  const int q0w = qt * 128 + wid * 32;        // wave's first Q row
  u16* const Pl = smem + 32768 + wid * 1024;  // [16][64] bf16 swizzled, reused A->B

  // Q fragments for both sub-tiles (scale folded in by k_rope_q)
  bf16x8 qfA[4], qfB[4];
  {
    const u16* qrowA = qbf + (size_t)(b * T_SEQ + q0w + lm) * 2048 + n * 128 + lg * 8;
    const u16* qrowB = qrowA + 16 * 2048;
#pragma unroll
    for (int c = 0; c < 4; ++c) {
      qfA[c] = *(const bf16x8*)(qrowA + c * 32);
      qfB[c] = *(const bf16x8*)(qrowB + c * 32);
    }
  }
  const u16* const kg = kbf + (size_t)(b * KVH + kh) * T_SEQ * 128;
  const u16* const vg = vt + (size_t)(b * KVH + kh) * 128 * T_SEQ;

  // swizzled LDS read offsets (elements); 16B-unit ^= (row&7)
  const int swz = lm & 7;
  int koff[4], voff[2], poff[4];
#pragma unroll
  for (int c = 0; c < 4; ++c) koff[c] = lm * 128 + (((c * 4 + lg) ^ swz) * 8);
#pragma unroll
  for (int ks = 0; ks < 2; ++ks) voff[ks] = lm * 64 + (((ks * 4 + lg) ^ swz) * 8);
#pragma unroll
  for (int st = 0; st < 4; ++st)
    poff[st] = lm * 64 + (((st * 2 + (lg >> 1)) ^ swz) * 8) + (lg & 1) * 4;

  const f32x4 z4 = {0.f, 0.f, 0.f, 0.f};
  f32x4 accA[8], accB[8];
#pragma unroll
  for (int h = 0; h < 8; ++h) { accA[h] = z4; accB[h] = z4; }
  float mA = -3.0e38f, lA = 0.f, mB = -3.0e38f, lB = 0.f;

  const int ntiles = 2 * qt + 2;

  // stage tile kb2 into buffer buf (linear LDS dest, inverse-swizzled gsrc)
  auto STAGE = [&](int buf, int kb2) {
    const int kv2 = kb2 * 64;
    const u16* ksrc = kg + (size_t)kv2 * 128;
    u16* kdst = Ks0 + buf * 8192;
    u16* vdst = Vs0 + buf * 8192;
#pragma unroll
    for (int i = 0; i < 4; ++i) {
      const int g = tid + i * 256;
      const int row = g >> 4, u = g & 15;
      gload16(ksrc + row * 128 + ((u ^ (row & 7)) * 8), kdst + g * 8);
    }
#pragma unroll
    for (int i = 0; i < 4; ++i) {
      const int g = tid + i * 256;
      const int row = g >> 3, u = g & 7;
      gload16(vg + (size_t)row * T_SEQ + kv2 + ((u ^ (row & 7)) * 8), vdst + g * 8);
    }
  };

  // softcap + online softmax + P->LDS bounce for one 16-row sub-tile
  auto tile_sm = [&](f32x4* sa, float& m_run, float& l_run, f32x4* acc,
                     bf16x8* pf, int tg, bool needMask, int kv) {
    float p[16];
#pragma unroll
    for (int st = 0; st < 4; ++st)
#pragma unroll
      for (int r = 0; r < 4; ++r) p[st * 4 + r] = sa[st][r];
    // softcap: 50*tanh(x/50) = 50 - 100/(exp(x/25)+1)
#pragma unroll
    for (int i = 0; i < 16; ++i) {
      const float e = __expf(p[i] * 0.04f);
      p[i] = 50.f - 100.f * __builtin_amdgcn_rcpf(e + 1.f);
    }
    if (needMask) {
#pragma unroll
      for (int i = 0; i < 16; ++i) {
        const int sg = kv + (i >> 2) * 16 + lg * 4 + (i & 3);
        if (sg > tg) p[i] = -3.0e38f;
      }
    }
    float mt = p[0];
#pragma unroll
    for (int i = 1; i < 16; ++i) mt = fmaxf(mt, p[i]);
    mt = fmaxf(mt, __shfl_xor(mt, 16));
    mt = fmaxf(mt, __shfl_xor(mt, 32));
    const float m_new = fmaxf(m_run, mt);
    const float alpha = __expf(m_run - m_new);
    float rs = 0.f;
#pragma unroll
    for (int i = 0; i < 16; ++i) {
      p[i] = __expf(p[i] - m_new);
      rs += p[i];
    }
    rs += __shfl_xor(rs, 16);
    rs += __shfl_xor(rs, 32);
    l_run = l_run * alpha + rs;
    m_run = m_new;

#pragma unroll
    for (int st = 0; st < 4; ++st) {
      ushort4 w4;
      w4.x = f2b(p[st * 4 + 0]);
      w4.y = f2b(p[st * 4 + 1]);
      w4.z = f2b(p[st * 4 + 2]);
      w4.w = f2b(p[st * 4 + 3]);
      *(ushort4*)(Pl + poff[st]) = w4;
    }
    asm volatile("s_waitcnt lgkmcnt(0)" ::: "memory");
#pragma unroll
    for (int ks = 0; ks < 2; ++ks) pf[ks] = *(const bf16x8*)(Pl + voff[ks]);

    float af[4];
#pragma unroll
    for (int r = 0; r < 4; ++r) af[r] = __shfl(alpha, lg * 4 + r);
#pragma unroll
    for (int h = 0; h < 8; ++h) {
      acc[h][0] *= af[0];
      acc[h][1] *= af[1];
      acc[h][2] *= af[2];
      acc[h][3] *= af[3];
    }
  };

  STAGE(0, 0);
  asm volatile("s_waitcnt vmcnt(0)" ::: "memory");
  __syncthreads();

  for (int kb = 0; kb < ntiles; ++kb) {
    const int cur = kb & 1;
    if (kb + 1 < ntiles) STAGE(cur ^ 1, kb + 1);
    const int kv = kb * 64;
    if (kv <= q0w + 31) {  // wave has unmasked rows in this KV tile
      const u16* KsC = Ks0 + cur * 8192;
      const u16* VsC = Vs0 + cur * 8192;

      f32x4 saA[4] = {z4, z4, z4, z4};
      f32x4 saB[4] = {z4, z4, z4, z4};
      __builtin_amdgcn_s_setprio(1);
#pragma unroll
      for (int st = 0; st < 4; ++st) {
#pragma unroll
        for (int c = 0; c < 4; ++c) {
          const bf16x8 kf = *(const bf16x8*)(KsC + st * 2048 + koff[c]);
          saA[st] = __builtin_amdgcn_mfma_f32_16x16x32_bf16(kf, qfA[c], saA[st], 0, 0, 0);
          saB[st] = __builtin_amdgcn_mfma_f32_16x16x32_bf16(kf, qfB[c], saB[st], 0, 0, 0);
        }
      }
      __builtin_amdgcn_s_setprio(0);

      bf16x8 pfA[2], pfB[2];
      tile_sm(saA, mA, lA, accA, pfA, q0w + lm, kv + 63 > q0w, kv);
      tile_sm(saB, mB, lB, accB, pfB, q0w + 16 + lm, kv + 63 > q0w + 16, kv);

      __builtin_amdgcn_s_setprio(1);
#pragma unroll
      for (int h = 0; h < 8; ++h) {
#pragma unroll
        for (int ks = 0; ks < 2; ++ks) {
          const bf16x8 vf = *(const bf16x8*)(VsC + h * 1024 + voff[ks]);
          accA[h] = __builtin_amdgcn_mfma_f32_16x16x32_bf16(pfA[ks], vf, accA[h], 0, 0, 0);
          accB[h] = __builtin_amdgcn_mfma_f32_16x16x32_bf16(pfB[ks], vf, accB[h], 0, 0, 0);
        }
      }
      __builtin_amdgcn_s_setprio(0);
    }
    asm volatile("s_waitcnt vmcnt(0)" ::: "memory");  // next-tile staging landed
    __syncthreads();
  }

  float liA[4], liB[4];
#pragma unroll
  for (int r = 0; r < 4; ++r) {
    liA[r] = 1.f / __shfl(lA, lg * 4 + r);
    liB[r] = 1.f / __shfl(lB, lg * 4 + r);
  }
#pragma unroll
  for (int h = 0; h < 8; ++h) {
#pragma unroll
    for (int r = 0; r < 4; ++r) {
      const size_t colo = n * 128 + h * 16 + lm;
      enc[(size_t)(b * T_SEQ + q0w + lg * 4 + r) * 2048 + colo] = f2b(accA[h][r] * liA[r]);
      enc[(size_t)(b * T_SEQ + q0w + 16 + lg * 4 + r) * 2048 + colo] = f2b(accB[h][r] * liB[r]);
    }
  }
}

extern "C" void kernel_launch(void* const* d_in, const int* in_sizes, int n_in,
                              void* d_out, int out_size, void* d_ws, size_t ws_size,
                              hipStream_t stream) {
  const float* x  = (const float*)d_in[0];
  const float* wq = (const float*)d_in[1];
  const float* wk = (const float*)d_in[2];
  const float* wv = (const float*)d_in[3];
  const float* wo = (const float*)d_in[4];

  char* ws = (char*)d_ws;
  u16* x_bf  = (u16*)(ws);                    // 16,777,216 B
  u16* wqkvt = (u16*)(ws + 16777216);         // 12,582,912 B  [3072][2048]
  u16* wot   = (u16*)(ws + 29360128);         //  8,388,608 B  [2048][2048]
  u16* qkv   = (u16*)(ws + 37748736);         // 25,165,824 B  [4096][3072]
  u16* enc   = qkv;                           // aliases qkv (dead by then)
  u16* q_bf  = (u16*)(ws + 62914560);         // 16,777,216 B  [4096][2048]
  u16* k_bf  = (u16*)(ws + 79691776);         //  4,194,304 B  [b][kh][t][h]
  u16* vt    = (u16*)(ws + 83886080);         //  4,194,304 B  [b][kh][h][t]
  if (ws_size < 88080384) return;             // need 84 MiB scratch
  (void)in_sizes; (void)n_in; (void)out_size;

  // 1) x -> bf16
  k_f32_to_bf16<<<dim3(8192), dim3(256), 0, stream>>>(x, x_bf, 8388608 / 4);
  // 2) weight transposes (fp32 [K][N] -> bf16 [N][K])
  k_transpose_f32_bf16<<<dim3(64, 64), dim3(32, 8), 0, stream>>>(wq, wqkvt, 2048, 2048);
  k_transpose_f32_bf16<<<dim3(16, 64), dim3(32, 8), 0, stream>>>(wk, wqkvt + 2048 * 2048, 2048, 512);
  k_transpose_f32_bf16<<<dim3(16, 64), dim3(32, 8), 0, stream>>>(wv, wqkvt + 2560 * 2048, 2048, 512);
  k_transpose_f32_bf16<<<dim3(64, 64), dim3(32, 8), 0, stream>>>(wo, wot, 2048, 2048);
  // 3) fused QKV projection: [4096][3072]
  k_gemm<1><<<dim3(32, 24), dim3(256), 0, stream>>>(x_bf, wqkvt, qkv,
                                                    4096, 3072, 2048, 2048, 2048, 3072);
  // 4) RoPE + layout shuffles
  k_rope_q<<<dim3(16384), dim3(256), 0, stream>>>(qkv, q_bf);
  k_rope_k<<<dim3(4096), dim3(256), 0, stream>>>(qkv, k_bf);
  k_v_transpose<<<dim3(64, 4, 8), dim3(32, 8), 0, stream>>>(qkv, vt);
  // 5) flash attention -> enc [4096][2048] bf16
  k_attn<<<dim3(16, 16, 2), dim3(256), 0, stream>>>(q_bf, k_bf, vt, enc);
  // 6) output projection -> d_out fp32
  k_gemm<0><<<dim3(32, 16), dim3(256), 0, stream>>>(enc, wot, d_out,
                                                    4096, 2048, 2048, 2048, 2048, 2048);
}

// Round 3
// 215.465 us; speedup vs baseline: 2.7553x; 1.2379x over previous
//
#include <hip/hip_runtime.h>
#include <stdint.h>

typedef unsigned short u16;
typedef __bf16 bf16x8 __attribute__((ext_vector_type(8)));
typedef float f32x4 __attribute__((ext_vector_type(4)));

#define T_SEQ 2048
#define KVH 4

__device__ __forceinline__ u16 f2b(float f) {
  uint32_t u = __builtin_bit_cast(uint32_t, f);
  u += 0x7FFFu + ((u >> 16) & 1u);
  return (u16)(u >> 16);
}
__device__ __forceinline__ float b2f(u16 h) {
  uint32_t u = ((uint32_t)h) << 16;
  return __builtin_bit_cast(float, u);
}

__device__ __forceinline__ void gload16(const void* g, void* l) {
  __builtin_amdgcn_global_load_lds((const __attribute__((address_space(1))) void*)g,
                                   (__attribute__((address_space(3))) void*)l, 16, 0, 0);
}

// ---------------- fp32 -> bf16 convert (x) ----------------
__global__ void k_f32_to_bf16(const float* __restrict__ in, u16* __restrict__ out, int n4) {
  int i = blockIdx.x * blockDim.x + threadIdx.x;
  if (i >= n4) return;
  float4 v = reinterpret_cast<const float4*>(in)[i];
  ushort4 o;
  o.x = f2b(v.x); o.y = f2b(v.y); o.z = f2b(v.z); o.w = f2b(v.w);
  reinterpret_cast<ushort4*>(out)[i] = o;
}

// ---------------- tiled transpose fp32[R][C] -> bf16[C][R] ----------------
__global__ void k_transpose_f32_bf16(const float* __restrict__ in, u16* __restrict__ out,
                                     int R, int Cc) {
  __shared__ float tile[32][33];
  const int c0 = blockIdx.x * 32, r0 = blockIdx.y * 32;
  const int tx = threadIdx.x, ty = threadIdx.y;
  for (int i = ty; i < 32; i += 8) tile[i][tx] = in[(size_t)(r0 + i) * Cc + c0 + tx];
  __syncthreads();
  for (int i = ty; i < 32; i += 8) out[(size_t)(c0 + i) * R + r0 + tx] = f2b(tile[tx][i]);
}

// ---------------- bf16 GEMM: C[M][N] = A[M][K] * Bt[N][K]^T ----------------
// 128x128 tile, 4 waves (2x2), BK=32, 16x16x32 MFMA, global_load_lds staging.
template <int OUT_BF16>
__global__ __launch_bounds__(256, 2) void k_gemm(const u16* __restrict__ A,
                                                 const u16* __restrict__ Bt,
                                                 void* __restrict__ Cp,
                                                 int M, int N, int Kd,
                                                 int lda, int ldb, int ldc) {
  __align__(16) __shared__ u16 As[128 * 32];
  __align__(16) __shared__ u16 Bs[128 * 32];
  const int tid = threadIdx.x;
  const int wid = tid >> 6, lane = tid & 63;
  const int lg = lane >> 4, lm = lane & 15;
  const int bm = blockIdx.x, bn = blockIdx.y;
  const int wr = wid >> 1, wc = wid & 1;

  const int srow = wid * 32 + (lane >> 2);
  const int scol = (lane & 3) * 8;
  const u16* ap0 = A + (size_t)(bm * 128 + srow) * lda + scol;
  const u16* ap1 = ap0 + (size_t)16 * lda;
  const u16* bp0 = Bt + (size_t)(bn * 128 + srow) * ldb + scol;
  const u16* bp1 = bp0 + (size_t)16 * ldb;
  u16* asDst0 = As + wid * 1024;
  u16* asDst1 = As + wid * 1024 + 512;
  u16* bsDst0 = Bs + wid * 1024;
  u16* bsDst1 = Bs + wid * 1024 + 512;

  const f32x4 z4 = {0.f, 0.f, 0.f, 0.f};
  f32x4 acc[4][4];
#pragma unroll
  for (int i = 0; i < 4; ++i)
#pragma unroll
    for (int j = 0; j < 4; ++j) acc[i][j] = z4;

  const int nk = Kd >> 5;
  for (int kb = 0; kb < nk; ++kb) {
    gload16(ap0, asDst0);
    gload16(ap1, asDst1);
    gload16(bp0, bsDst0);
    gload16(bp1, bsDst1);
    ap0 += 32; ap1 += 32; bp0 += 32; bp1 += 32;
    __syncthreads();
    bf16x8 af[4], bfr[4];
#pragma unroll
    for (int i = 0; i < 4; ++i)
      af[i] = *(const bf16x8*)(As + (wr * 64 + i * 16 + lm) * 32 + lg * 8);
#pragma unroll
    for (int j = 0; j < 4; ++j)
      bfr[j] = *(const bf16x8*)(Bs + (wc * 64 + j * 16 + lm) * 32 + lg * 8);
#pragma unroll
    for (int i = 0; i < 4; ++i)
#pragma unroll
      for (int j = 0; j < 4; ++j)
        acc[i][j] = __builtin_amdgcn_mfma_f32_16x16x32_bf16(af[i], bfr[j], acc[i][j], 0, 0, 0);
    __syncthreads();
  }

#pragma unroll
  for (int i = 0; i < 4; ++i) {
    const int row = bm * 128 + wr * 64 + i * 16 + lg * 4;
#pragma unroll
    for (int j = 0; j < 4; ++j) {
      const int col = bn * 128 + wc * 64 + j * 16 + lm;
#pragma unroll
      for (int r = 0; r < 4; ++r) {
        const float v = acc[i][j][r];
        if (OUT_BF16)
          ((u16*)Cp)[(size_t)(row + r) * ldc + col] = f2b(v);
        else
          ((float*)Cp)[(size_t)(row + r) * ldc + col] = v;
      }
    }
  }
}

// ---------------- RoPE for Q (+ fold 1/sqrt(H) scale) ----------------
__global__ void k_rope_q(const u16* __restrict__ qkv, u16* __restrict__ qbf) {
  const int idx = blockIdx.x * 256 + threadIdx.x;  // B*T*N*64 threads
  const int j = idx & 63;
  const int n = (idx >> 6) & 15;
  const int m = idx >> 10;  // b*T + t
  const int t = m & (T_SEQ - 1);
  const float inv = __expf((float)j * -0.14391157f);  // 10000^(-j/64)
  const float ang = (float)t * inv;
  float s, c;
  __sincosf(ang, &s, &c);
  const u16* row = qkv + (size_t)m * 3072 + n * 128;
  const float x1 = b2f(row[j]), x2 = b2f(row[j + 64]);
  const float scale = 0.08838834764831845f;  // 1/sqrt(128)
  u16* orow = qbf + (size_t)m * 2048 + n * 128;
  orow[j] = f2b((x1 * c - x2 * s) * scale);
  orow[j + 64] = f2b((x2 * c + x1 * s) * scale);
}

// ---------------- RoPE for K, layout [b][kh][t][h] ----------------
__global__ void k_rope_k(const u16* __restrict__ qkv, u16* __restrict__ kbf) {
  const int idx = blockIdx.x * 256 + threadIdx.x;  // B*T*KVH*64 threads
  const int j = idx & 63;
  const int kh = (idx >> 6) & 3;
  const int m = idx >> 8;  // b*T + t
  const int t = m & (T_SEQ - 1);
  const int b = m >> 11;
  const float inv = __expf((float)j * -0.14391157f);
  const float ang = (float)t * inv;
  float s, c;
  __sincosf(ang, &s, &c);
  const u16* row = qkv + (size_t)m * 3072 + 2048 + kh * 128;
  const float x1 = b2f(row[j]), x2 = b2f(row[j + 64]);
  u16* orow = kbf + ((size_t)(b * KVH + kh) * T_SEQ + t) * 128;
  orow[j] = f2b(x1 * c - x2 * s);
  orow[j + 64] = f2b(x2 * c + x1 * s);
}

// ---------------- V transpose: qkv[.,2560+kh*128+h] -> vt[b][kh][h][t] ----------------
__global__ void k_v_transpose(const u16* __restrict__ qkv, u16* __restrict__ vt) {
  __shared__ u16 tile[32][33];
  const int t0 = blockIdx.x * 32, h0 = blockIdx.y * 32, bk = blockIdx.z;
  const int b = bk >> 2, kh = bk & 3;
  const int tx = threadIdx.x, ty = threadIdx.y;
  for (int i = ty; i < 32; i += 8)
    tile[i][tx] = qkv[(size_t)(b * T_SEQ + t0 + i) * 3072 + 2560 + kh * 128 + h0 + tx];
  __syncthreads();
  for (int i = ty; i < 32; i += 8)
    vt[(size_t)bk * (128 * T_SEQ) + (size_t)(h0 + i) * T_SEQ + t0 + tx] = tile[tx][i];
}

// ---------------- Flash attention with tanh softcap + causal ----------------
// grid (16, N=16, B=2), 4 waves x 32 Q rows (two 16-row sub-tiles A,B).
// FIXED-MAX softmax: softcap bounds logits at 50, so p~ = exp(p-50) needs no
// running max / alpha / rescale. Fused: p~ = exp2(-144.2695/(exp2(.0577*x)+1)).
// Row-sum is a per-lane scalar, reduced once at the end.
// Work pairing: qt = (b==0) ? 15-bx : bx so co-dispatched blocks f and f+256
// (same CU under round-robin) total a constant 36 KV-tile iterations.
__global__ __launch_bounds__(256, 2) void k_attn(const u16* __restrict__ qbf,
                                                 const u16* __restrict__ kbf,
                                                 const u16* __restrict__ vt,
                                                 u16* __restrict__ enc) {
  // LDS: Ks dbuf 2*16KB | Vs dbuf 2*16KB | Pl 4 waves * 2KB  = 73728 B
  __shared__ __align__(16) u16 smem[36864];
  u16* const Ks0 = smem;            // + buf*8192
  u16* const Vs0 = smem + 16384;    // + buf*8192

  const int n = blockIdx.y, b = blockIdx.z;
  const int qt = (b == 0) ? (15 - blockIdx.x) : blockIdx.x;  // balanced pairing
  const int kh = n >> 2;
  const int tid = threadIdx.x;
  const int wid = tid >> 6;
  const int lane = tid & 63;
  const int lg = lane >> 4;
  const int lm = lane & 15;
  const int q0w = qt * 128 + wid * 32;        // wave's first Q row
  u16* const Pl = smem + 32768 + wid * 1024;  // [16][64] bf16 swizzled, reused A->B

  // Q fragments for both sub-tiles (scale folded in by k_rope_q)
  bf16x8 qfA[4], qfB[4];
  {
    const u16* qrowA = qbf + (size_t)(b * T_SEQ + q0w + lm) * 2048 + n * 128 + lg * 8;
    const u16* qrowB = qrowA + 16 * 2048;
#pragma unroll
    for (int c = 0; c < 4; ++c) {
      qfA[c] = *(const bf16x8*)(qrowA + c * 32);
      qfB[c] = *(const bf16x8*)(qrowB + c * 32);
    }
  }
  const u16* const kg = kbf + (size_t)(b * KVH + kh) * T_SEQ * 128;
  const u16* const vg = vt + (size_t)(b * KVH + kh) * 128 * T_SEQ;

  // swizzled LDS read offsets (elements); 16B-unit ^= (row&7)
  const int swz = lm & 7;
  int koff[4], voff[2], poff[4];
#pragma unroll
  for (int c = 0; c < 4; ++c) koff[c] = lm * 128 + (((c * 4 + lg) ^ swz) * 8);
#pragma unroll
  for (int ks = 0; ks < 2; ++ks) voff[ks] = lm * 64 + (((ks * 4 + lg) ^ swz) * 8);
#pragma unroll
  for (int st = 0; st < 4; ++st)
    poff[st] = lm * 64 + (((st * 2 + (lg >> 1)) ^ swz) * 8) + (lg & 1) * 4;

  const f32x4 z4 = {0.f, 0.f, 0.f, 0.f};
  f32x4 accA[8], accB[8];
#pragma unroll
  for (int h = 0; h < 8; ++h) { accA[h] = z4; accB[h] = z4; }
  float lA = 0.f, lB = 0.f;  // per-lane partial row-sums (row lm, this lane's s-slices)

  const int ntiles = 2 * qt + 2;

  // stage tile kb2 into buffer buf (linear LDS dest, inverse-swizzled gsrc)
  auto STAGE = [&](int buf, int kb2) {
    const int kv2 = kb2 * 64;
    const u16* ksrc = kg + (size_t)kv2 * 128;
    u16* kdst = Ks0 + buf * 8192;
    u16* vdst = Vs0 + buf * 8192;
#pragma unroll
    for (int i = 0; i < 4; ++i) {
      const int g = tid + i * 256;
      const int row = g >> 4, u = g & 15;
      gload16(ksrc + row * 128 + ((u ^ (row & 7)) * 8), kdst + g * 8);
    }
#pragma unroll
    for (int i = 0; i < 4; ++i) {
      const int g = tid + i * 256;
      const int row = g >> 3, u = g & 7;
      gload16(vg + (size_t)row * T_SEQ + kv2 + ((u ^ (row & 7)) * 8), vdst + g * 8);
    }
  };

  // fixed-max softcap+softmax for one 16-row sub-tile; no cross-lane ops.
  auto tile_p = [&](f32x4* sa, float& lsum, bf16x8* pf, int tg, bool needMask, int kv) {
    float p[16];
#pragma unroll
    for (int st = 0; st < 4; ++st)
#pragma unroll
      for (int r = 0; r < 4; ++r) p[st * 4 + r] = sa[st][r];
    // p~ = exp(50*tanh(x/50) - 50) = exp2(-144.269504 / (exp2(x*0.05770780) + 1))
#pragma unroll
    for (int i = 0; i < 16; ++i) {
      const float e = __builtin_amdgcn_exp2f(p[i] * 0.05770780163555853f);
      p[i] = __builtin_amdgcn_exp2f(-144.269504088896f * __builtin_amdgcn_rcpf(e + 1.f));
    }
    if (needMask) {
#pragma unroll
      for (int i = 0; i < 16; ++i) {
        const int sg = kv + (i >> 2) * 16 + lg * 4 + (i & 3);
        if (sg > tg) p[i] = 0.f;
      }
    }
#pragma unroll
    for (int i = 0; i < 16; ++i) lsum += p[i];
#pragma unroll
    for (int st = 0; st < 4; ++st) {
      ushort4 w4;
      w4.x = f2b(p[st * 4 + 0]);
      w4.y = f2b(p[st * 4 + 1]);
      w4.z = f2b(p[st * 4 + 2]);
      w4.w = f2b(p[st * 4 + 3]);
      *(ushort4*)(Pl + poff[st]) = w4;
    }
    asm volatile("s_waitcnt lgkmcnt(0)" ::: "memory");
#pragma unroll
    for (int ks = 0; ks < 2; ++ks) pf[ks] = *(const bf16x8*)(Pl + voff[ks]);
  };

  STAGE(0, 0);
  asm volatile("s_waitcnt vmcnt(0)" ::: "memory");
  __syncthreads();

  for (int kb = 0; kb < ntiles; ++kb) {
    const int cur = kb & 1;
    if (kb + 1 < ntiles) STAGE(cur ^ 1, kb + 1);
    const int kv = kb * 64;
    if (kv <= q0w + 31) {  // wave has unmasked rows in this KV tile
      const u16* KsC = Ks0 + cur * 8192;
      const u16* VsC = Vs0 + cur * 8192;

      f32x4 saA[4] = {z4, z4, z4, z4};
      f32x4 saB[4] = {z4, z4, z4, z4};
      __builtin_amdgcn_s_setprio(1);
#pragma unroll
      for (int st = 0; st < 4; ++st) {
#pragma unroll
        for (int c = 0; c < 4; ++c) {
          const bf16x8 kf = *(const bf16x8*)(KsC + st * 2048 + koff[c]);
          saA[st] = __builtin_amdgcn_mfma_f32_16x16x32_bf16(kf, qfA[c], saA[st], 0, 0, 0);
          saB[st] = __builtin_amdgcn_mfma_f32_16x16x32_bf16(kf, qfB[c], saB[st], 0, 0, 0);
        }
      }
      __builtin_amdgcn_s_setprio(0);

      bf16x8 pfA[2], pfB[2];
      tile_p(saA, lA, pfA, q0w + lm, kv + 63 > q0w, kv);
      tile_p(saB, lB, pfB, q0w + 16 + lm, kv + 63 > q0w + 16, kv);

      __builtin_amdgcn_s_setprio(1);
#pragma unroll
      for (int h = 0; h < 8; ++h) {
#pragma unroll
        for (int ks = 0; ks < 2; ++ks) {
          const bf16x8 vf = *(const bf16x8*)(VsC + h * 1024 + voff[ks]);
          accA[h] = __builtin_amdgcn_mfma_f32_16x16x32_bf16(pfA[ks], vf, accA[h], 0, 0, 0);
          accB[h] = __builtin_amdgcn_mfma_f32_16x16x32_bf16(pfB[ks], vf, accB[h], 0, 0, 0);
        }
      }
      __builtin_amdgcn_s_setprio(0);
    }
    asm volatile("s_waitcnt vmcnt(0)" ::: "memory");  // next-tile staging landed
    __syncthreads();
  }

  // reduce row-sums across the 4 lg lanes sharing a row, then normalize.
  lA += __shfl_xor(lA, 16); lA += __shfl_xor(lA, 32);
  lB += __shfl_xor(lB, 16); lB += __shfl_xor(lB, 32);
  float liA[4], liB[4];
#pragma unroll
  for (int r = 0; r < 4; ++r) {
    liA[r] = 1.f / __shfl(lA, lg * 4 + r);
    liB[r] = 1.f / __shfl(lB, lg * 4 + r);
  }
#pragma unroll
  for (int h = 0; h < 8; ++h) {
#pragma unroll
    for (int r = 0; r < 4; ++r) {
      const size_t colo = n * 128 + h * 16 + lm;
      enc[(size_t)(b * T_SEQ + q0w + lg * 4 + r) * 2048 + colo] = f2b(accA[h][r] * liA[r]);
      enc[(size_t)(b * T_SEQ + q0w + 16 + lg * 4 + r) * 2048 + colo] = f2b(accB[h][r] * liB[r]);
    }
  }
}

extern "C" void kernel_launch(void* const* d_in, const int* in_sizes, int n_in,
                              void* d_out, int out_size, void* d_ws, size_t ws_size,
                              hipStream_t stream) {
  const float* x  = (const float*)d_in[0];
  const float* wq = (const float*)d_in[1];
  const float* wk = (const float*)d_in[2];
  const float* wv = (const float*)d_in[3];
  const float* wo = (const float*)d_in[4];

  char* ws = (char*)d_ws;
  u16* x_bf  = (u16*)(ws);                    // 16,777,216 B
  u16* wqkvt = (u16*)(ws + 16777216);         // 12,582,912 B  [3072][2048]
  u16* wot   = (u16*)(ws + 29360128);         //  8,388,608 B  [2048][2048]
  u16* qkv   = (u16*)(ws + 37748736);         // 25,165,824 B  [4096][3072]
  u16* enc   = qkv;                           // aliases qkv (dead by then)
  u16* q_bf  = (u16*)(ws + 62914560);         // 16,777,216 B  [4096][2048]
  u16* k_bf  = (u16*)(ws + 79691776);         //  4,194,304 B  [b][kh][t][h]
  u16* vt    = (u16*)(ws + 83886080);         //  4,194,304 B  [b][kh][h][t]
  if (ws_size < 88080384) return;             // need 84 MiB scratch
  (void)in_sizes; (void)n_in; (void)out_size;

  // 1) x -> bf16
  k_f32_to_bf16<<<dim3(8192), dim3(256), 0, stream>>>(x, x_bf, 8388608 / 4);
  // 2) weight transposes (fp32 [K][N] -> bf16 [N][K])
  k_transpose_f32_bf16<<<dim3(64, 64), dim3(32, 8), 0, stream>>>(wq, wqkvt, 2048, 2048);
  k_transpose_f32_bf16<<<dim3(16, 64), dim3(32, 8), 0, stream>>>(wk, wqkvt + 2048 * 2048, 2048, 512);
  k_transpose_f32_bf16<<<dim3(16, 64), dim3(32, 8), 0, stream>>>(wv, wqkvt + 2560 * 2048, 2048, 512);
  k_transpose_f32_bf16<<<dim3(64, 64), dim3(32, 8), 0, stream>>>(wo, wot, 2048, 2048);
  // 3) fused QKV projection: [4096][3072]
  k_gemm<1><<<dim3(32, 24), dim3(256), 0, stream>>>(x_bf, wqkvt, qkv,
                                                    4096, 3072, 2048, 2048, 2048, 3072);
  // 4) RoPE + layout shuffles
  k_rope_q<<<dim3(16384), dim3(256), 0, stream>>>(qkv, q_bf);
  k_rope_k<<<dim3(4096), dim3(256), 0, stream>>>(qkv, k_bf);
  k_v_transpose<<<dim3(64, 4, 8), dim3(32, 8), 0, stream>>>(qkv, vt);
  // 5) flash attention -> enc [4096][2048] bf16
  k_attn<<<dim3(16, 16, 2), dim3(256), 0, stream>>>(q_bf, k_bf, vt, enc);
  // 6) output projection -> d_out fp32
  k_gemm<0><<<dim3(32, 16), dim3(256), 0, stream>>>(enc, wot, d_out,
                                                    4096, 2048, 2048, 2048, 2048, 2048);
}